// Round 2
// baseline (395.680 us; speedup 1.0000x reference)
//
#include <hip/hip_runtime.h>

// PoolingRetriever collapses: softmax over a size-1 axis == 1.0, so
//   out = (x @ Wv.T + bv) @ Wo.T + bo
// x: (65536,768) f32. Wv: (64,768). Wo: (768,64). out: (65536,768) f32.
//
// R2: R0/R1 showed waves x per-wave-ILP constant => perf constant (126us,
// 2.4 TB/s, VGPR=32: compiler serialized each wave to ~1 load in flight).
// This version forces memory-level parallelism:
//   Phase 1: explicit depth-1 software pipeline (prefetch next kc's x pair +
//            4 B-frags into named regs while current MFMAs run).
//   Phase 2: prefetch next cc's 8 B-frags; stores go through a per-wave LDS
//            transpose -> 4 dense nontemporal dwordx4 stores per cc
//            (16 rows x 64B segments) instead of 16 scattered dword stores.
// sV (phase-1.5 transpose) aliases the sOut buffer (used sequentially).

#define DIM 768
#define NB  64
#define KC  (DIM / 32)          // 24 k-chunks of 32
#define RPW 16                  // rows per wave (one 16-row MFMA strip)
#define WPB 4                   // waves per block (256 threads)
#define RPB (RPW * WPB)         // 64 rows per block
#define WV_ELEMS (NB * DIM)     // 49152 per weight matrix

typedef __attribute__((ext_vector_type(8))) short short8;
typedef __attribute__((ext_vector_type(4))) float f32x4;

__device__ __forceinline__ unsigned short f2bf(float f) {
    union { float f; unsigned int u; } v; v.f = f;
    return (unsigned short)((v.u + 0x7fffu + ((v.u >> 16) & 1u)) >> 16);
}

__device__ __forceinline__ short8 pack_bf8(float4 lo, float4 hi) {
    short8 r;
    r[0] = (short)f2bf(lo.x); r[1] = (short)f2bf(lo.y);
    r[2] = (short)f2bf(lo.z); r[3] = (short)f2bf(lo.w);
    r[4] = (short)f2bf(hi.x); r[5] = (short)f2bf(hi.y);
    r[6] = (short)f2bf(hi.z); r[7] = (short)f2bf(hi.w);
    return r;
}

// Pack Wv and Wo (f32, row-major) into bf16 MFMA B-fragment order.
// pWv frag (kc,t): element idx ((kc*4+t)*64 + lane)*8 + j holds
//   Wv[n = t*16 + (lane&15)][k = kc*32 + (lane>>4)*8 + j]
// pWo frag (tile,h): element idx ((tile*2+h)*64 + lane)*8 + j holds
//   Wo[n = tile*16 + (lane&15)][jd = h*32 + (lane>>4)*8 + j]
__global__ void pack_weights(const float* __restrict__ Wv, const float* __restrict__ Wo,
                             unsigned short* __restrict__ pWv, unsigned short* __restrict__ pWo) {
    int e = blockIdx.x * 256 + threadIdx.x;      // 0 .. 2*49152-1
    int which = (e >= WV_ELEMS) ? 1 : 0;
    int idx = which ? e - WV_ELEMS : e;
    int frag = idx >> 9;                          // per-frag: 64 lanes * 8 elems
    int lane = (idx >> 3) & 63;
    int j = idx & 7;
    int lm = lane & 15, lq = lane >> 4;
    float v;
    if (!which) {
        int kc = frag >> 2, t = frag & 3;
        v = Wv[(t * 16 + lm) * DIM + kc * 32 + lq * 8 + j];
    } else {
        int tile = frag >> 1, h = frag & 1;
        v = Wo[(tile * 16 + lm) * NB + h * 32 + lq * 8 + j];
    }
    (which ? pWo : pWv)[idx] = f2bf(v);
}

__global__ __launch_bounds__(256, 4)
void pr_main(const float* __restrict__ x,
             const unsigned short* __restrict__ pWv, const float* __restrict__ bv,
             const unsigned short* __restrict__ pWo, const float* __restrict__ bo,
             float* __restrict__ out)
{
    // Per-wave slab, used twice: first as bf16 sV[16][72] (phase-1.5
    // transpose), then as f32 sOut[16][72] (phase-2 store transpose).
    __shared__ float sOut[WPB][RPW][72];          // 4*16*72*4 = 18432 B

    const int tid  = threadIdx.x;
    const int wave = tid >> 6;
    const int lane = tid & 63;
    const int lq   = lane >> 4;
    const int lm   = lane & 15;
    const long row0 = (long)blockIdx.x * RPB + wave * RPW;

    unsigned short* sV = (unsigned short*)&sOut[wave][0][0];   // [16][72] bf16 view

    // ---------------- Phase 1: V = x @ Wv.T (pipelined) -------------------
    f32x4 accV[4];
    #pragma unroll
    for (int t = 0; t < 4; ++t) accV[t] = (f32x4){0.f, 0.f, 0.f, 0.f};

    const float* xb = x + (row0 + lm) * DIM + lq * 8;
    const short8* wv = (const short8*)pWv + lane;   // + frag*64

    float4 al = *(const float4*)(xb);
    float4 ah = *(const float4*)(xb + 4);
    short8 b0 = wv[0 * 64], b1 = wv[1 * 64], b2 = wv[2 * 64], b3 = wv[3 * 64];

    #pragma unroll 4
    for (int kc = 0; kc < KC; ++kc) {
        const int kn = (kc + 1 < KC) ? kc + 1 : kc;     // tail: redundant reload
        float4 nal = *(const float4*)(xb + kn * 32);
        float4 nah = *(const float4*)(xb + kn * 32 + 4);
        short8 nb0 = wv[(kn * 4 + 0) * 64];
        short8 nb1 = wv[(kn * 4 + 1) * 64];
        short8 nb2 = wv[(kn * 4 + 2) * 64];
        short8 nb3 = wv[(kn * 4 + 3) * 64];

        const short8 a = pack_bf8(al, ah);
        accV[0] = __builtin_amdgcn_mfma_f32_16x16x32_bf16(a, b0, accV[0], 0, 0, 0);
        accV[1] = __builtin_amdgcn_mfma_f32_16x16x32_bf16(a, b1, accV[1], 0, 0, 0);
        accV[2] = __builtin_amdgcn_mfma_f32_16x16x32_bf16(a, b2, accV[2], 0, 0, 0);
        accV[3] = __builtin_amdgcn_mfma_f32_16x16x32_bf16(a, b3, accV[3], 0, 0, 0);

        al = nal; ah = nah;
        b0 = nb0; b1 = nb1; b2 = nb2; b3 = nb3;
    }

    // ------- Phase 1.5: V + bv -> LDS (bf16), C-layout -> A-layout --------
    #pragma unroll
    for (int t = 0; t < 4; ++t) {
        const float bvn = bv[t * 16 + lm];
        #pragma unroll
        for (int r = 0; r < 4; ++r) {
            sV[(lq * 4 + r) * 72 + t * 16 + lm] = f2bf(accV[t][r] + bvn);
        }
    }
    __syncthreads();
    const short8 aV0 = *(const short8*)&sV[lm * 72 + lq * 8];
    const short8 aV1 = *(const short8*)&sV[lm * 72 + 32 + lq * 8];

    // ---------------- Phase 2: out = V @ Wo.T + bo (pipelined) ------------
    const short8* wo = (const short8*)pWo + lane;   // + frag*64
    short8 cb[8];
    #pragma unroll
    for (int i = 0; i < 8; ++i) cb[i] = wo[i * 64];

    const int sr = lane >> 2;          // store row 0..15
    const int sc = lane & 3;           // store col-quad 0..3
    float* orow = out + (row0 + sr) * DIM + sc * 4;

    for (int cc = 0; cc < 12; ++cc) {
        const int cn = (cc + 1 < 12) ? cc + 1 : cc;
        short8 nb[8];
        #pragma unroll
        for (int i = 0; i < 8; ++i) nb[i] = wo[(cn * 8 + i) * 64];

        f32x4 acc[4];
        #pragma unroll
        for (int t = 0; t < 4; ++t) acc[t] = (f32x4){0.f, 0.f, 0.f, 0.f};
        #pragma unroll
        for (int t = 0; t < 4; ++t) {
            acc[t] = __builtin_amdgcn_mfma_f32_16x16x32_bf16(aV0, cb[2 * t + 0], acc[t], 0, 0, 0);
            acc[t] = __builtin_amdgcn_mfma_f32_16x16x32_bf16(aV1, cb[2 * t + 1], acc[t], 0, 0, 0);
        }

        // C-layout (+bias) -> per-wave LDS slab
        #pragma unroll
        for (int t = 0; t < 4; ++t) {
            const float boc = bo[cc * 64 + t * 16 + lm];
            #pragma unroll
            for (int r = 0; r < 4; ++r) {
                sOut[wave][lq * 4 + r][t * 16 + lm] = acc[t][r] + boc;
            }
        }
        // Same-wave cross-lane LDS exchange: DS pipe is in-order per wave;
        // the waitcnt + sched_barrier stop the compiler hoisting the reads.
        asm volatile("s_waitcnt lgkmcnt(0)" ::: "memory");
        __builtin_amdgcn_sched_barrier(0);

        // Dense stores: 4 instrs, each 16 rows x 64B contiguous segments.
        #pragma unroll
        for (int k = 0; k < 4; ++k) {
            const f32x4 v = *(const f32x4*)&sOut[wave][sr][k * 16 + sc * 4];
            __builtin_nontemporal_store(v, (f32x4*)(orow + cc * 64 + k * 16));
        }
        __builtin_amdgcn_wave_barrier();   // keep next cc's LDS writes after these reads

        #pragma unroll
        for (int i = 0; i < 8; ++i) cb[i] = nb[i];
    }
}

extern "C" void kernel_launch(void* const* d_in, const int* in_sizes, int n_in,
                              void* d_out, int out_size, void* d_ws, size_t ws_size,
                              hipStream_t stream) {
    const float* x  = (const float*)d_in[0];
    // d_in[1..5] = q_state, Wq, bq, Wk, bk — mathematically dead: softmax over
    // the size-1 sequence axis is identically 1, so out depends only on v path.
    const float* Wv = (const float*)d_in[6];
    const float* bv = (const float*)d_in[7];
    const float* Wo = (const float*)d_in[8];
    const float* bo = (const float*)d_in[9];
    float* out = (float*)d_out;

    unsigned short* pWv = (unsigned short*)d_ws;          // 96 KB
    unsigned short* pWo = pWv + WV_ELEMS;                 // 96 KB

    pack_weights<<<dim3(2 * WV_ELEMS / 256), dim3(256), 0, stream>>>(Wv, Wo, pWv, pWo);

    const int Bn = in_sizes[0] / DIM;                     // 65536
    pr_main<<<dim3(Bn / RPB), dim3(256), 0, stream>>>(x, pWv, bv, pWo, bo, out);
}